// Round 19
// baseline (120.757 us; speedup 1.0000x reference)
//
#include <hip/hip_runtime.h>
#include <hip/hip_bf16.h>

#define N_NODES 65536
#define N_EDGES 1048576
#define DIM 64
#define NXCD 8
#define SLOT_CAP 64            // P(Poisson(16) >= 64) ~ 2e-18: exact here
#define BIN_BLOCKS 512         // pass-1 blocks, 2048 edges each
#define NBUCKET 64             // bucket = dst >> 10 (1024 nodes per bucket)
#define BUCKET_NODES 128       // per scatter_b block (8 sub-blocks per bucket)
#define CAP_XB 2432            // per (xcd,bucket): mean 2048 + ~8.5 sigma

typedef float f32x4 __attribute__((ext_vector_type(4)));
typedef unsigned short u16x4 __attribute__((ext_vector_type(4)));
typedef unsigned short u16x8 __attribute__((ext_vector_type(8)));

__device__ __forceinline__ float lrelu(float x) { return x >= 0.f ? x : 0.01f * x; }
__device__ __forceinline__ float bf2f(unsigned short h) {
    return __uint_as_float(((unsigned)h) << 16);
}
__device__ __forceinline__ unsigned short f2bf(float f) {
    return __bfloat16_as_ushort(__float2bfloat16(f));  // RNE
}

// ---- tiny zero kernel for the 512-word bin counters ----
__global__ __launch_bounds__(256) void zero_bins(unsigned* __restrict__ p) {
    p[blockIdx.x * 256 + threadIdx.x] = 0u;
}

// ---- pass 1: fused {s0/t0, fbfF=bf16(features)} + 64-bucket binning with
// LDS sort. Histogram (64 LDS counters) -> wave scan -> block-batched reserve
// atomics (XCD-private counters, L2-local) -> LDS sort by bucket -> dump in
// runs of ~32 consecutive u32 (coalesced lines; the old 512-bucket version
// touched ~1 line per 4B store). No per-edge global atomics.
__global__ __launch_bounds__(256) void prep_bin64(
    const float* __restrict__ feats, const float* __restrict__ attn_w,
    const int* __restrict__ src, const int* __restrict__ dst,
    float* __restrict__ s0, float* __restrict__ t0,
    unsigned short* __restrict__ fbfF,
    unsigned* __restrict__ bin_cnt,      // [8][64]
    unsigned* __restrict__ bucket) {     // [8][64][CAP_XB]
    __shared__ unsigned lcnt[NBUCKET], lbase[NBUCKET], lstart[NBUCKET];
    __shared__ unsigned sorted[2048];
    int tid = threadIdx.x;
    int lane = tid & 63;
    int g = lane >> 4, l16 = lane & 15;
    int wave_id = blockIdx.x * 4 + (tid >> 6);   // [0, 2048)
    int grp16 = wave_id * 4 + g;                 // [0, 8192)

    // feature pass: 16-lane group per node, f32x4 loads, 4-stage reduces
    f32x4 aw_s4 = ((const f32x4*)attn_w)[l16];
    f32x4 aw_t4 = ((const f32x4*)attn_w)[16 + l16];
    #pragma unroll
    for (int it = 0; it < 8; ++it) {
        int node = grp16 + it * 8192;
        f32x4 f4 = ((const f32x4*)feats)[node * 16 + l16];
        u16x4 ub = {f2bf(f4[0]), f2bf(f4[1]), f2bf(f4[2]), f2bf(f4[3])};
        ((u16x4*)fbfF)[node * 16 + l16] = ub;
        float sp = f4[0]*aw_s4[0] + f4[1]*aw_s4[1] + f4[2]*aw_s4[2] + f4[3]*aw_s4[3];
        float tq = f4[0]*aw_t4[0] + f4[1]*aw_t4[1] + f4[2]*aw_t4[2] + f4[3]*aw_t4[3];
        #pragma unroll
        for (int off = 1; off < 16; off <<= 1) {
            sp += __shfl_xor(sp, off);
            tq += __shfl_xor(tq, off);
        }
        if (l16 == 0) { s0[node] = sp; t0[node] = tq; }
    }

    // histogram: 2048 edges per block
    if (tid < NBUCKET) lcnt[tid] = 0;
    __syncthreads();
    unsigned pk[8];
    unsigned short rk[8];
    int ebase = blockIdx.x * 2048;
    #pragma unroll
    for (int it = 0; it < 8; ++it) {
        int e = ebase + it * 256 + tid;
        unsigned d = (unsigned)dst[e], v = (unsigned)src[e];
        pk[it] = (d << 16) | v;
        rk[it] = (unsigned short)atomicAdd(&lcnt[d >> 10], 1u);
    }
    __syncthreads();
    int xcd = blockIdx.x & (NXCD - 1);
    // wave 0: exclusive scan of 64 counts + global reserve (L2-local)
    if (tid < 64) {
        unsigned c = lcnt[tid];
        unsigned x = c;
        #pragma unroll
        for (int off = 1; off < 64; off <<= 1) {
            unsigned y = __shfl_up(x, off);
            if (tid >= off) x += y;
        }
        lstart[tid] = x - c;  // exclusive
        lbase[tid] = atomicAdd(&bin_cnt[xcd * NBUCKET + tid], c);
    }
    __syncthreads();
    // LDS sort by bucket
    #pragma unroll
    for (int it = 0; it < 8; ++it)
        sorted[lstart[pk[it] >> 26] + rk[it]] = pk[it];
    __syncthreads();
    // coalesced run dump
    unsigned* bb = bucket + (size_t)xcd * NBUCKET * CAP_XB;
    for (int j = tid; j < 2048; j += 256) {
        unsigned p = sorted[j];
        unsigned bkt = p >> 26;                       // dst >> 10
        unsigned pos = lbase[bkt] + ((unsigned)j - lstart[bkt]);
        if (pos < CAP_XB) bb[bkt * CAP_XB + pos] = p;
    }
}

// ---- pass 2: block b owns nodes [128b, 128b+128) = sub-range of parent
// bucket b>>3. Scans the parent's 8 per-XCD sub-buckets (L2-resident, 1/8
// hit rate), LDS-atomic slot fill, fully-coalesced tile dump. No global
// atomics.
__global__ __launch_bounds__(256) void scatter_b(
    const unsigned* __restrict__ bucket, const unsigned* __restrict__ bin_cnt,
    unsigned* __restrict__ deg, unsigned short* __restrict__ csr_slot) {
    __shared__ unsigned short slots[BUCKET_NODES * SLOT_CAP];  // 16 KB
    __shared__ unsigned cur[BUCKET_NODES];
    int tid = threadIdx.x;
    int b = blockIdx.x;                     // [0, 512)
    int pb = b >> 3;                        // parent bucket [0, 64)
    unsigned lo = (unsigned)b * BUCKET_NODES;
    if (tid < BUCKET_NODES) cur[tid] = 0;
    __syncthreads();
    #pragma unroll
    for (int x = 0; x < NXCD; ++x) {
        unsigned cnt = min(bin_cnt[x * NBUCKET + pb], (unsigned)CAP_XB);
        const unsigned* bb = bucket + ((size_t)x * NBUCKET + pb) * CAP_XB;
        for (unsigned i = tid; i < cnt; i += 256) {
            unsigned p = bb[i];
            unsigned rel = (p >> 16) - lo;
            if (rel < (unsigned)BUCKET_NODES) {
                unsigned pos = atomicAdd(&cur[rel], 1u);
                if (pos < SLOT_CAP) slots[(rel << 6) + pos] = (unsigned short)(p & 0xFFFFu);
            }
        }
    }
    __syncthreads();
    u16x4* dv = (u16x4*)(csr_slot + (size_t)lo * SLOT_CAP);
    const u16x4* sv = (const u16x4*)slots;
    for (int j = tid; j < BUCKET_NODES * SLOT_CAP / 4; j += 256)
        dv[j] = sv[j];
    if (tid < BUCKET_NODES) deg[lo + tid] = cur[tid];
}

// ---- main aggregation (r18-proven, byte-identical): one 8-lane group per
// dst node, u16x8 lane loads, packed broadcasts, per-group trip count,
// deferred-out epilogue (last hop combines F/A1/A2/a4; single out write).
__global__ __launch_bounds__(256) void node_agg(
    const unsigned short* __restrict__ feats_bf,   // gather source (F, A1, or A2)
    const unsigned short* __restrict__ fbfF,       // last hop: F rows
    const unsigned short* __restrict__ fbfA1,      // last hop: A1 rows
    const float* __restrict__ s_in, const float* __restrict__ t_in,
    const unsigned* __restrict__ deg_arr, const unsigned short* __restrict__ csr_slot,
    const float* __restrict__ attn_w, const float* __restrict__ attn_b,
    const float* __restrict__ temp, int last,
    unsigned short* __restrict__ feats_out_bf,
    float* __restrict__ s_next, float* __restrict__ t_next,
    float* __restrict__ out) {
    int tid = threadIdx.x;
    int lane = tid & 63;
    int wv = blockIdx.x * 4 + (tid >> 6);   // wave id [0, 8192)
    int g = lane >> 3, l8 = lane & 7;       // 8 groups of 8 lanes
    int node = wv * 8 + g;

    float tp = t_in[node];                  // group-uniform
    float b = attn_b[0];
    int deg = min((int)deg_arr[node], SLOT_CAP);

    u16x8 sl = ((const u16x8*)csr_slot)[node * 8 + l8];
    unsigned pk[8];
    #pragma unroll
    for (int je = 0; je < 8; ++je) {
        int idx = l8 * 8 + je;
        bool v = idx < deg;
        int sj = v ? (int)sl[je] : 0;       // gate stale-slot probes to hot line
        float ev = v ? __expf(lrelu(s_in[sj] + tp + b)) : 0.f;
        pk[je] = (((unsigned)f2bf(ev)) << 16) | (unsigned)sj;
    }

    f32x4 accL = {0.f, 0.f, 0.f, 0.f};
    f32x4 accH = {0.f, 0.f, 0.f, 0.f};
    float dn = 0.f;
    const u16x8* feats8 = (const u16x8*)feats_bf;  // 8 u16x8 per row
    int gbase = lane & 56;                  // g * 8
    for (int bl = 0; bl * 8 < deg; ++bl) {  // per-group count; intra-group shuffles
        #pragma unroll
        for (int je = 0; je < 8; ++je) {
            unsigned p = __shfl(pk[je], gbase + bl);
            float w = __uint_as_float(p & 0xFFFF0000u);
            u16x8 q = feats8[(p & 0xFFFFu) * 8 + l8];
            accL[0] += w * bf2f(q[0]);
            accL[1] += w * bf2f(q[1]);
            accL[2] += w * bf2f(q[2]);
            accL[3] += w * bf2f(q[3]);
            accH[0] += w * bf2f(q[4]);
            accH[1] += w * bf2f(q[5]);
            accH[2] += w * bf2f(q[6]);
            accH[3] += w * bf2f(q[7]);
            dn += w;
        }
    }
    float inv = (deg > 0) ? 1.f / dn : 0.f;
    f32x4 aL = accL * inv, aH = accH * inv;

    if (!last) {
        u16x8 ub = {f2bf(aL[0]), f2bf(aL[1]), f2bf(aL[2]), f2bf(aL[3]),
                    f2bf(aH[0]), f2bf(aH[1]), f2bf(aH[2]), f2bf(aH[3])};
        ((u16x8*)feats_out_bf)[node * 8 + l8] = ub;
        f32x4 awsL = ((const f32x4*)attn_w)[l8 * 2];
        f32x4 awsH = ((const f32x4*)attn_w)[l8 * 2 + 1];
        f32x4 awtL = ((const f32x4*)attn_w)[16 + l8 * 2];
        f32x4 awtH = ((const f32x4*)attn_w)[16 + l8 * 2 + 1];
        float sp = aL[0]*awsL[0] + aL[1]*awsL[1] + aL[2]*awsL[2] + aL[3]*awsL[3]
                 + aH[0]*awsH[0] + aH[1]*awsH[1] + aH[2]*awsH[2] + aH[3]*awsH[3];
        float tq = aL[0]*awtL[0] + aL[1]*awtL[1] + aL[2]*awtL[2] + aL[3]*awtL[3]
                 + aH[0]*awtH[0] + aH[1]*awtH[1] + aH[2]*awtH[2] + aH[3]*awtH[3];
        #pragma unroll
        for (int off = 1; off < 8; off <<= 1) {
            sp += __shfl_xor(sp, off);
            tq += __shfl_xor(tq, off);
        }
        if (l8 == 0) { s_next[node] = sp; t_next[node] = tq; }
    } else {
        u16x8 fF = ((const u16x8*)fbfF)[node * 8 + l8];
        u16x8 fA1 = ((const u16x8*)fbfA1)[node * 8 + l8];
        u16x8 fA2 = ((const u16x8*)feats_bf)[node * 8 + l8];
        float t0 = temp[0], t1 = temp[1], t2 = temp[2], t3 = temp[3];
        f32x4 oL, oH;
        #pragma unroll
        for (int i = 0; i < 4; ++i) {
            oL[i] = t0 * bf2f(fF[i]) + t1 * bf2f(fA1[i]) + t2 * bf2f(fA2[i]) + t3 * aL[i];
            oH[i] = t0 * bf2f(fF[i + 4]) + t1 * bf2f(fA1[i + 4]) + t2 * bf2f(fA2[i + 4]) + t3 * aH[i];
        }
        ((f32x4*)out)[node * 16 + l8 * 2] = oL;
        ((f32x4*)out)[node * 16 + l8 * 2 + 1] = oH;
    }
}

extern "C" void kernel_launch(void* const* d_in, const int* in_sizes, int n_in,
                              void* d_out, int out_size, void* d_ws, size_t ws_size,
                              hipStream_t stream) {
    const float* features = (const float*)d_in[0];
    const int* src = (const int*)d_in[1];
    const int* dst = (const int*)d_in[2];
    const float* attn_w = (const float*)d_in[3];
    const float* attn_b = (const float*)d_in[4];
    const float* temp = (const float*)d_in[5];
    float* out = (float*)d_out;

    // workspace (~33 MB): s/t pairs, deg, bin_cnt, csr slots, F + A1 bf16
    // buffers, and a shared region for {bucket (5 MB, passes 1-2 only),
    // A2 (8 MB, hops 1-2 only)} -- bucket is dead before A2 is written.
    float* s0 = (float*)d_ws;                          // N
    float* s1 = s0 + N_NODES;                          // N
    float* t0 = s1 + N_NODES;                          // N
    float* t1 = t0 + N_NODES;                          // N
    unsigned* deg = (unsigned*)(t1 + N_NODES);         // N (written by scatter_b)
    unsigned* bin_cnt = deg + N_NODES;                 // 8*64 (+pad)
    unsigned short* csr_slot = (unsigned short*)(bin_cnt + 512);  // N*64 u16 (8 MB)
    unsigned short* fbfF = csr_slot + (size_t)N_NODES * SLOT_CAP; // N*DIM bf16
    unsigned short* fbfA1 = fbfF + (size_t)N_NODES * DIM;         // N*DIM bf16
    unsigned* bucket = (unsigned*)(fbfA1 + (size_t)N_NODES * DIM);  // 8*64*CAP_XB u32
    unsigned short* fbfA2 = (unsigned short*)bucket;   // aliases bucket (dead by hop 1)

    const int AGG_BLOCKS = N_NODES / 32;     // 2048 (32 nodes per block)

    zero_bins<<<2, 256, 0, stream>>>(bin_cnt);
    prep_bin64<<<BIN_BLOCKS, 256, 0, stream>>>(features, attn_w, src, dst,
                                               s0, t0, fbfF, bin_cnt, bucket);
    scatter_b<<<512, 256, 0, stream>>>(bucket, bin_cnt, deg, csr_slot);

    // ---- 3 hops: F -> A1 -> A2 -> out (deferred-out accumulation) ----
    node_agg<<<AGG_BLOCKS, 256, 0, stream>>>(fbfF, fbfF, fbfA1, s0, t0, deg, csr_slot,
                                             attn_w, attn_b, temp, 0,
                                             fbfA1, s1, t1, out);
    node_agg<<<AGG_BLOCKS, 256, 0, stream>>>(fbfA1, fbfF, fbfA1, s1, t1, deg, csr_slot,
                                             attn_w, attn_b, temp, 0,
                                             fbfA2, s0, t0, out);
    node_agg<<<AGG_BLOCKS, 256, 0, stream>>>(fbfA2, fbfF, fbfA1, s0, t0, deg, csr_slot,
                                             attn_w, attn_b, temp, 1,
                                             (unsigned short*)0, s1, t1, out);
}

// Round 20
// 103.580 us; speedup vs baseline: 1.1658x; 1.1658x over previous
//
#include <hip/hip_runtime.h>
#include <hip/hip_bf16.h>

#define N_NODES 65536
#define N_EDGES 1048576
#define DIM 64
#define NXCD 8
#define SLOT_CAP 64            // P(Poisson(16) >= 64) ~ 2e-18: exact here
#define BIN_BLOCKS 512         // pass-1 blocks, 2048 edges each
#define NBUCKET 512            // bucket = dst >> 7 (128 nodes per bucket)
#define BUCKET_NODES 128
#define CAP_XB 384             // per (xcd,bucket) capacity: mean 256 + 8 sigma

typedef float f32x4 __attribute__((ext_vector_type(4)));
typedef unsigned short u16x4 __attribute__((ext_vector_type(4)));
typedef unsigned short u16x8 __attribute__((ext_vector_type(8)));

__device__ __forceinline__ float lrelu(float x) { return x >= 0.f ? x : 0.01f * x; }
__device__ __forceinline__ float bf2f(unsigned short h) {
    return __uint_as_float(((unsigned)h) << 16);
}
__device__ __forceinline__ unsigned short f2bf(float f) {
    return __bfloat16_as_ushort(__float2bfloat16(f));  // RNE
}

// ---- tiny zero kernel: 16 KB bin counters ----
__global__ __launch_bounds__(256) void zero_bins(unsigned* __restrict__ p) {
    p[blockIdx.x * 256 + threadIdx.x] = 0u;
}

// ---- pass 1 (r16/r18-proven): fused {s0/t0, fbfF=bf16(features)} + fine
// binning by dst>>7. LDS histogram -> block-batched reserve atomics into the
// XCD-private counter copy -> edge writes into the XCD-private bucket copy
// (only same-XCD blocks share bucket lines -> writes combine in that L2).
// No per-edge global atomics.
__global__ __launch_bounds__(256) void prep_bin512(
    const float* __restrict__ feats, const float* __restrict__ attn_w,
    const int* __restrict__ src, const int* __restrict__ dst,
    float* __restrict__ s0, float* __restrict__ t0,
    unsigned short* __restrict__ fbfF,
    unsigned* __restrict__ bin_cnt,      // [8][512]
    unsigned* __restrict__ bucket) {     // [8][512][CAP_XB]
    __shared__ unsigned lcnt[NBUCKET];
    __shared__ unsigned lbase[NBUCKET];
    int tid = threadIdx.x;
    int lane = tid & 63;
    int g = lane >> 4, l16 = lane & 15;
    int wave_id = blockIdx.x * 4 + (tid >> 6);   // [0, 2048)
    int grp16 = wave_id * 4 + g;                 // [0, 8192)

    f32x4 aw_s4 = ((const f32x4*)attn_w)[l16];
    f32x4 aw_t4 = ((const f32x4*)attn_w)[16 + l16];
    #pragma unroll
    for (int it = 0; it < 8; ++it) {
        int node = grp16 + it * 8192;
        f32x4 f4 = ((const f32x4*)feats)[node * 16 + l16];
        u16x4 ub = {f2bf(f4[0]), f2bf(f4[1]), f2bf(f4[2]), f2bf(f4[3])};
        ((u16x4*)fbfF)[node * 16 + l16] = ub;
        float sp = f4[0]*aw_s4[0] + f4[1]*aw_s4[1] + f4[2]*aw_s4[2] + f4[3]*aw_s4[3];
        float tq = f4[0]*aw_t4[0] + f4[1]*aw_t4[1] + f4[2]*aw_t4[2] + f4[3]*aw_t4[3];
        #pragma unroll
        for (int off = 1; off < 16; off <<= 1) {
            sp += __shfl_xor(sp, off);
            tq += __shfl_xor(tq, off);
        }
        if (l16 == 0) { s0[node] = sp; t0[node] = tq; }
    }

    for (int i = tid; i < NBUCKET; i += 256) lcnt[i] = 0;
    __syncthreads();
    unsigned pk[8];
    unsigned short rk[8];
    int ebase = blockIdx.x * 2048;
    #pragma unroll
    for (int it = 0; it < 8; ++it) {
        int e = ebase + it * 256 + tid;
        unsigned d = (unsigned)dst[e], v = (unsigned)src[e];
        pk[it] = (d << 16) | v;
        rk[it] = (unsigned short)atomicAdd(&lcnt[d >> 7], 1u);
    }
    __syncthreads();
    int xcd = blockIdx.x & (NXCD - 1);
    unsigned* bc = bin_cnt + xcd * NBUCKET;
    for (int i = tid; i < NBUCKET; i += 256)
        lbase[i] = atomicAdd(&bc[i], lcnt[i]);   // L2-local, block-batched
    __syncthreads();
    unsigned* bb = bucket + (size_t)xcd * NBUCKET * CAP_XB;
    #pragma unroll
    for (int it = 0; it < 8; ++it) {
        unsigned bkt = pk[it] >> 23;             // dst >> 7
        unsigned pos = lbase[bkt] + rk[it];
        if (pos < CAP_XB) bb[bkt * CAP_XB + pos] = pk[it];
    }
}

// ---- pass 2 (r16/r18-proven): block b owns bucket b == nodes [128b,128b+128).
// Reads its 8 per-XCD sub-buckets (contiguous, zero filter waste), LDS-atomic
// slot fill, fully-coalesced tile dump. No global atomics.
__global__ __launch_bounds__(256) void scatter_b(
    const unsigned* __restrict__ bucket, const unsigned* __restrict__ bin_cnt,
    unsigned* __restrict__ deg, unsigned short* __restrict__ csr_slot) {
    __shared__ unsigned short slots[BUCKET_NODES * SLOT_CAP];  // 16 KB
    __shared__ unsigned cur[BUCKET_NODES];
    int tid = threadIdx.x;
    int b = blockIdx.x;                     // [0, 512)
    unsigned lo = (unsigned)b * BUCKET_NODES;
    if (tid < BUCKET_NODES) cur[tid] = 0;
    __syncthreads();
    #pragma unroll
    for (int x = 0; x < NXCD; ++x) {
        unsigned cnt = min(bin_cnt[x * NBUCKET + b], (unsigned)CAP_XB);
        const unsigned* bb = bucket + ((size_t)x * NBUCKET + b) * CAP_XB;
        for (unsigned i = tid; i < cnt; i += 256) {
            unsigned p = bb[i];
            unsigned rel = (p >> 16) - lo;  // in [0,128) by construction
            unsigned pos = atomicAdd(&cur[rel], 1u);
            if (pos < SLOT_CAP) slots[(rel << 6) + pos] = (unsigned short)(p & 0xFFFFu);
        }
    }
    __syncthreads();
    u16x4* dv = (u16x4*)(csr_slot + (size_t)lo * SLOT_CAP);
    const u16x4* sv = (const u16x4*)slots;
    for (int j = tid; j < BUCKET_NODES * SLOT_CAP / 4; j += 256)
        dv[j] = sv[j];
    if (tid < BUCKET_NODES) deg[lo + tid] = cur[tid];
}

// ---- main aggregation (r18-proven): one 8-lane group per dst node, u16x8
// lane loads, packed (bf16(w)<<16|src) broadcasts, per-group trip count
// (convergence-safe: intra-group shuffles, group exits together), deferred-
// out epilogue (last hop combines F/A1/A2/a4; out written exactly once).
__global__ __launch_bounds__(256) void node_agg(
    const unsigned short* __restrict__ feats_bf,   // gather source (F, A1, or A2)
    const unsigned short* __restrict__ fbfF,       // last hop: F rows
    const unsigned short* __restrict__ fbfA1,      // last hop: A1 rows
    const float* __restrict__ s_in, const float* __restrict__ t_in,
    const unsigned* __restrict__ deg_arr, const unsigned short* __restrict__ csr_slot,
    const float* __restrict__ attn_w, const float* __restrict__ attn_b,
    const float* __restrict__ temp, int last,
    unsigned short* __restrict__ feats_out_bf,
    float* __restrict__ s_next, float* __restrict__ t_next,
    float* __restrict__ out) {
    int tid = threadIdx.x;
    int lane = tid & 63;
    int wv = blockIdx.x * 4 + (tid >> 6);   // wave id [0, 8192)
    int g = lane >> 3, l8 = lane & 7;       // 8 groups of 8 lanes
    int node = wv * 8 + g;

    float tp = t_in[node];                  // group-uniform
    float b = attn_b[0];
    int deg = min((int)deg_arr[node], SLOT_CAP);

    // slot row: 8 lanes x u16x8 = 64 slots (128B contiguous)
    u16x8 sl = ((const u16x8*)csr_slot)[node * 8 + l8];
    unsigned pk[8];
    #pragma unroll
    for (int je = 0; je < 8; ++je) {
        int idx = l8 * 8 + je;
        bool v = idx < deg;
        int sj = v ? (int)sl[je] : 0;       // gate stale-slot probes to hot line
        float ev = v ? __expf(lrelu(s_in[sj] + tp + b)) : 0.f;
        pk[je] = (((unsigned)f2bf(ev)) << 16) | (unsigned)sj;
    }

    f32x4 accL = {0.f, 0.f, 0.f, 0.f};
    f32x4 accH = {0.f, 0.f, 0.f, 0.f};
    float dn = 0.f;
    const u16x8* feats8 = (const u16x8*)feats_bf;  // 8 u16x8 per row
    int gbase = lane & 56;                  // g * 8
    for (int bl = 0; bl * 8 < deg; ++bl) {  // per-group count; intra-group shuffles
        #pragma unroll
        for (int je = 0; je < 8; ++je) {
            unsigned p = __shfl(pk[je], gbase + bl);
            float w = __uint_as_float(p & 0xFFFF0000u);
            u16x8 q = feats8[(p & 0xFFFFu) * 8 + l8];
            accL[0] += w * bf2f(q[0]);
            accL[1] += w * bf2f(q[1]);
            accL[2] += w * bf2f(q[2]);
            accL[3] += w * bf2f(q[3]);
            accH[0] += w * bf2f(q[4]);
            accH[1] += w * bf2f(q[5]);
            accH[2] += w * bf2f(q[6]);
            accH[3] += w * bf2f(q[7]);
            dn += w;
        }
    }
    float inv = (deg > 0) ? 1.f / dn : 0.f;
    f32x4 aL = accL * inv, aH = accH * inv;

    if (!last) {
        // intermediate hop: bf16 result + next-hop s/t only (no out traffic)
        u16x8 ub = {f2bf(aL[0]), f2bf(aL[1]), f2bf(aL[2]), f2bf(aL[3]),
                    f2bf(aH[0]), f2bf(aH[1]), f2bf(aH[2]), f2bf(aH[3])};
        ((u16x8*)feats_out_bf)[node * 8 + l8] = ub;
        f32x4 awsL = ((const f32x4*)attn_w)[l8 * 2];
        f32x4 awsH = ((const f32x4*)attn_w)[l8 * 2 + 1];
        f32x4 awtL = ((const f32x4*)attn_w)[16 + l8 * 2];
        f32x4 awtH = ((const f32x4*)attn_w)[16 + l8 * 2 + 1];
        float sp = aL[0]*awsL[0] + aL[1]*awsL[1] + aL[2]*awsL[2] + aL[3]*awsL[3]
                 + aH[0]*awsH[0] + aH[1]*awsH[1] + aH[2]*awsH[2] + aH[3]*awsH[3];
        float tq = aL[0]*awtL[0] + aL[1]*awtL[1] + aL[2]*awtL[2] + aL[3]*awtL[3]
                 + aH[0]*awtH[0] + aH[1]*awtH[1] + aH[2]*awtH[2] + aH[3]*awtH[3];
        #pragma unroll
        for (int off = 1; off < 8; off <<= 1) {
            sp += __shfl_xor(sp, off);
            tq += __shfl_xor(tq, off);
        }
        if (l8 == 0) { s_next[node] = sp; t_next[node] = tq; }
    } else {
        // final hop: out = t0*F + t1*A1 + t2*A2 + t3*a4 (single out write)
        u16x8 fF = ((const u16x8*)fbfF)[node * 8 + l8];
        u16x8 fA1 = ((const u16x8*)fbfA1)[node * 8 + l8];
        u16x8 fA2 = ((const u16x8*)feats_bf)[node * 8 + l8];
        float t0 = temp[0], t1 = temp[1], t2 = temp[2], t3 = temp[3];
        f32x4 oL, oH;
        #pragma unroll
        for (int i = 0; i < 4; ++i) {
            oL[i] = t0 * bf2f(fF[i]) + t1 * bf2f(fA1[i]) + t2 * bf2f(fA2[i]) + t3 * aL[i];
            oH[i] = t0 * bf2f(fF[i + 4]) + t1 * bf2f(fA1[i + 4]) + t2 * bf2f(fA2[i + 4]) + t3 * aH[i];
        }
        ((f32x4*)out)[node * 16 + l8 * 2] = oL;
        ((f32x4*)out)[node * 16 + l8 * 2 + 1] = oH;
    }
}

extern "C" void kernel_launch(void* const* d_in, const int* in_sizes, int n_in,
                              void* d_out, int out_size, void* d_ws, size_t ws_size,
                              hipStream_t stream) {
    const float* features = (const float*)d_in[0];
    const int* src = (const int*)d_in[1];
    const int* dst = (const int*)d_in[2];
    const float* attn_w = (const float*)d_in[3];
    const float* attn_b = (const float*)d_in[4];
    const float* temp = (const float*)d_in[5];
    float* out = (float*)d_out;

    // workspace (~33.3 MB): s/t pairs, deg, bin_cnt, csr slots, F + A1 bf16
    // buffers, and a shared 8 MB region for {bucket (pass 1-2 only), A2
    // (hops 1-2 only)} -- bucket is dead before A2 is written.
    float* s0 = (float*)d_ws;                          // N
    float* s1 = s0 + N_NODES;                          // N
    float* t0 = s1 + N_NODES;                          // N
    float* t1 = t0 + N_NODES;                          // N
    unsigned* deg = (unsigned*)(t1 + N_NODES);         // N (written by scatter_b)
    unsigned* bin_cnt = deg + N_NODES;                 // 8*512
    unsigned short* csr_slot = (unsigned short*)(bin_cnt + NXCD * NBUCKET); // N*64 u16
    unsigned short* fbfF = csr_slot + (size_t)N_NODES * SLOT_CAP;           // N*DIM bf16
    unsigned short* fbfA1 = fbfF + (size_t)N_NODES * DIM;                   // N*DIM bf16
    unsigned* bucket = (unsigned*)(fbfA1 + (size_t)N_NODES * DIM);  // 8*512*CAP_XB u32
    unsigned short* fbfA2 = (unsigned short*)bucket;   // aliases bucket (dead by hop 1)

    const int AGG_BLOCKS = N_NODES / 32;     // 2048 (32 nodes per block)

    zero_bins<<<16, 256, 0, stream>>>(bin_cnt);
    prep_bin512<<<BIN_BLOCKS, 256, 0, stream>>>(features, attn_w, src, dst,
                                                s0, t0, fbfF, bin_cnt, bucket);
    scatter_b<<<NBUCKET, 256, 0, stream>>>(bucket, bin_cnt, deg, csr_slot);

    // ---- 3 hops: F -> A1 -> A2 -> out (deferred-out accumulation) ----
    node_agg<<<AGG_BLOCKS, 256, 0, stream>>>(fbfF, fbfF, fbfA1, s0, t0, deg, csr_slot,
                                             attn_w, attn_b, temp, 0,
                                             fbfA1, s1, t1, out);
    node_agg<<<AGG_BLOCKS, 256, 0, stream>>>(fbfA1, fbfF, fbfA1, s1, t1, deg, csr_slot,
                                             attn_w, attn_b, temp, 0,
                                             fbfA2, s0, t0, out);
    node_agg<<<AGG_BLOCKS, 256, 0, stream>>>(fbfA2, fbfF, fbfA1, s0, t0, deg, csr_slot,
                                             attn_w, attn_b, temp, 1,
                                             (unsigned short*)0, s1, t1, out);
}